// Round 18
// baseline (850.465 us; speedup 1.0000x reference)
//
#include <hip/hip_runtime.h>
#include <hip/hip_bf16.h>

typedef unsigned short u16;
typedef __bf16 bf16x8 __attribute__((ext_vector_type(8)));
typedef unsigned short u16x8 __attribute__((ext_vector_type(8)));
typedef unsigned short u16x4 __attribute__((ext_vector_type(4)));
typedef float f32x4 __attribute__((ext_vector_type(4)));

#define DI static __device__ __forceinline__

DI u16 f2bf(float f) {
    unsigned u = __builtin_bit_cast(unsigned, f);
    u += 0x7FFFu + ((u >> 16) & 1u);   // round-to-nearest-even
    return (u16)(u >> 16);
}
DI float bf2f(u16 u) {
    unsigned x = ((unsigned)u) << 16;
    return __builtin_bit_cast(float, x);
}
DI u16x8 ld8_f32(const float* __restrict__ p) {
    const float4 a = *(const float4*)p;
    const float4 b = *(const float4*)(p + 4);
    u16x8 r = { f2bf(a.x), f2bf(a.y), f2bf(a.z), f2bf(a.w),
                f2bf(b.x), f2bf(b.y), f2bf(b.z), f2bf(b.w) };
    return r;
}
DI f32x4 mfma16(u16x8 a, u16x8 b, f32x4 c) {
    return __builtin_amdgcn_mfma_f32_16x16x32_bf16(
        __builtin_bit_cast(bf16x8, a), __builtin_bit_cast(bf16x8, b), c, 0, 0, 0);
}

// ---------------------------------------------------------------- cast ----
__global__ void __launch_bounds__(256) k_cast(const float* __restrict__ in,
                                              u16* __restrict__ out, long n4) {
    long i = (long)blockIdx.x * 256 + threadIdx.x;
    if (i >= n4) return;
    const float4 v = *(const float4*)(in + i * 4);
    u16x4 o = { f2bf(v.x), f2bf(v.y), f2bf(v.z), f2bf(v.w) };
    *(u16x4*)(out + i * 4) = o;
}

// ---------------------------------------------------------------- GEMM ----
// R11/R12-verified best 128x128 (see history R7/R10/R13/R14 for rejects).
template <int AF32, int BF32>
__global__ void __launch_bounds__(256, 2) k_gemm_bt(
    const void* __restrict__ Ap, long lda,
    const void* __restrict__ Bp, long ldb,
    float* __restrict__ Cf, u16* __restrict__ Cb, long ldc,
    const float* __restrict__ bias, int relu, int accum, float alpha, int K,
    int Hdiv, long sAb, long sAh, long sBb, long sBh, long sCb, long sCh)
{
    __shared__ __align__(16) u16 As[128 * 72];
    __shared__ __align__(16) u16 Bs[128 * 72];
    const int tid  = threadIdx.x;
    const int lane = tid & 63, wave = tid >> 6;
    const int r16  = lane & 15, quad = lane >> 4;
    const int wr   = (wave >> 1) * 64, wc = (wave & 1) * 64;
    const int zb = blockIdx.z / Hdiv, zh = blockIdx.z % Hdiv;
    const long aoff = (long)zb * sAb + (long)zh * sAh + (long)blockIdx.x * 128 * lda;
    const long boff = (long)zb * sBb + (long)zh * sBh + (long)blockIdx.y * 128 * ldb;
    const u16*   A16 = (const u16*)Ap + aoff;
    const float* A32 = (const float*)Ap + aoff;
    const u16*   B16 = (const u16*)Bp + boff;
    const float* B32 = (const float*)Bp + boff;
    const long coff = (long)zb * sCb + (long)zh * sCh +
                      (long)blockIdx.x * 128 * ldc + (long)blockIdx.y * 128;

    f32x4 acc[4][4];
#pragma unroll
    for (int i = 0; i < 4; i++)
#pragma unroll
        for (int j = 0; j < 4; j++) acc[i][j] = f32x4{0.f, 0.f, 0.f, 0.f};

    const int st_row = tid >> 3;
    const int st_col = (tid & 7) * 8;

    u16x8 ar0, ar1, ar2, ar3, br0, br1, br2, br3;

#define LDAB(KS)                                                              \
    do {                                                                      \
        const long kk0_ = (long)(KS) * 64 + st_col;                           \
        if constexpr (AF32) {                                                 \
            ar0 = ld8_f32(A32 + (long)(st_row)      * lda + kk0_);            \
            ar1 = ld8_f32(A32 + (long)(st_row + 32) * lda + kk0_);            \
            ar2 = ld8_f32(A32 + (long)(st_row + 64) * lda + kk0_);            \
            ar3 = ld8_f32(A32 + (long)(st_row + 96) * lda + kk0_);            \
        } else {                                                              \
            ar0 = *(const u16x8*)(A16 + (long)(st_row)      * lda + kk0_);    \
            ar1 = *(const u16x8*)(A16 + (long)(st_row + 32) * lda + kk0_);    \
            ar2 = *(const u16x8*)(A16 + (long)(st_row + 64) * lda + kk0_);    \
            ar3 = *(const u16x8*)(A16 + (long)(st_row + 96) * lda + kk0_);    \
        }                                                                     \
        if constexpr (BF32) {                                                 \
            br0 = ld8_f32(B32 + (long)(st_row)      * ldb + kk0_);            \
            br1 = ld8_f32(B32 + (long)(st_row + 32) * ldb + kk0_);            \
            br2 = ld8_f32(B32 + (long)(st_row + 64) * ldb + kk0_);            \
            br3 = ld8_f32(B32 + (long)(st_row + 96) * ldb + kk0_);            \
        } else {                                                              \
            br0 = *(const u16x8*)(B16 + (long)(st_row)      * ldb + kk0_);    \
            br1 = *(const u16x8*)(B16 + (long)(st_row + 32) * ldb + kk0_);    \
            br2 = *(const u16x8*)(B16 + (long)(st_row + 64) * ldb + kk0_);    \
            br3 = *(const u16x8*)(B16 + (long)(st_row + 96) * ldb + kk0_);    \
        }                                                                     \
    } while (0)

#define STAB()                                                                \
    do {                                                                      \
        u16* ap_ = As + st_row * 72 + st_col;                                 \
        *(u16x8*)(ap_)            = ar0;                                      \
        *(u16x8*)(ap_ + 32 * 72)  = ar1;                                      \
        *(u16x8*)(ap_ + 64 * 72)  = ar2;                                      \
        *(u16x8*)(ap_ + 96 * 72)  = ar3;                                      \
        u16* bp_ = Bs + st_row * 72 + st_col;                                 \
        *(u16x8*)(bp_)            = br0;                                      \
        *(u16x8*)(bp_ + 32 * 72)  = br1;                                      \
        *(u16x8*)(bp_ + 64 * 72)  = br2;                                      \
        *(u16x8*)(bp_ + 96 * 72)  = br3;                                      \
    } while (0)

    LDAB(0);
    STAB();
    __syncthreads();

    const int nks = K >> 6;
    for (int ks = 0; ks < nks; ks++) {
        const bool more = (ks + 1 < nks);
        if (more) LDAB(ks + 1);
#pragma unroll
        for (int kk = 0; kk < 64; kk += 32) {
            u16x8 af[4], bfr[4];
#pragma unroll
            for (int i = 0; i < 4; i++)
                af[i] = *(const u16x8*)(As + (wr + i * 16 + r16) * 72 + kk + 8 * quad);
#pragma unroll
            for (int j = 0; j < 4; j++)
                bfr[j] = *(const u16x8*)(Bs + (wc + j * 16 + r16) * 72 + kk + 8 * quad);
#pragma unroll
            for (int i = 0; i < 4; i++)
#pragma unroll
                for (int j = 0; j < 4; j++)
                    acc[i][j] = mfma16(af[i], bfr[j], acc[i][j]);
        }
        __syncthreads();
        if (more) {
            STAB();
            __syncthreads();
        }
    }
#undef LDAB
#undef STAB

#pragma unroll
    for (int i = 0; i < 4; i++) {
#pragma unroll
        for (int j = 0; j < 4; j++) {
            const int gcol = wc + j * 16 + r16;
            const float bv = bias ? bias[blockIdx.y * 128 + gcol] : 0.f;
#pragma unroll
            for (int r = 0; r < 4; r++) {
                const long o = coff + (long)(wr + i * 16 + quad * 4 + r) * ldc + gcol;
                float v = acc[i][j][r] * alpha + bv;
                if (accum) v += Cf[o];
                if (relu) v = fmaxf(v, 0.f);
                if (Cf) Cf[o] = v;
                if (Cb) Cb[o] = f2bf(v);
            }
        }
    }
}

// --------------------------------------- GEMM 256x128 (bf16, FFN GEMM1) ----
// 8 waves: wave>>1 selects one of 4 64-row groups (wr spans 0..192 = the
// FULL 256 rows), wave&1 selects the 64-col half. R17 bug was an extra <<1
// on wr (rows 256..447 OOB). Staging bytes/MFMA 1.33x better than 128^2.
__global__ void __launch_bounds__(512, 2) k_gemm256(
    const u16* __restrict__ A, long lda,
    const u16* __restrict__ B, long ldb,
    u16* __restrict__ Cb, long ldc,
    const float* __restrict__ bias, int relu, int K)
{
    __shared__ __align__(16) u16 As[256 * 72];
    __shared__ __align__(16) u16 Bs[128 * 72];
    const int tid  = threadIdx.x;
    const int lane = tid & 63, wave = tid >> 6;          // wave 0..7
    const int r16  = lane & 15, quad = lane >> 4;
    const int wr   = (wave >> 1) * 64, wc = (wave & 1) * 64;
    const u16* Ab = A + (long)blockIdx.x * 256 * lda;
    const u16* Bb = B + (long)blockIdx.y * 128 * ldb;
    const long coff = (long)blockIdx.x * 256 * ldc + blockIdx.y * 128;

    f32x4 acc[4][4];
#pragma unroll
    for (int i = 0; i < 4; i++)
#pragma unroll
        for (int j = 0; j < 4; j++) acc[i][j] = f32x4{0.f, 0.f, 0.f, 0.f};

    const int st_row = tid >> 3;          // 0..63 (+64r)
    const int st_col = (tid & 7) * 8;

    u16x8 ar0, ar1, ar2, ar3, br0, br1;

#define LDAB(KS)                                                              \
    do {                                                                      \
        const long kk0_ = (long)(KS) * 64 + st_col;                           \
        ar0 = *(const u16x8*)(Ab + (long)(st_row)       * lda + kk0_);        \
        ar1 = *(const u16x8*)(Ab + (long)(st_row + 64)  * lda + kk0_);        \
        ar2 = *(const u16x8*)(Ab + (long)(st_row + 128) * lda + kk0_);        \
        ar3 = *(const u16x8*)(Ab + (long)(st_row + 192) * lda + kk0_);        \
        br0 = *(const u16x8*)(Bb + (long)(st_row)       * ldb + kk0_);        \
        br1 = *(const u16x8*)(Bb + (long)(st_row + 64)  * ldb + kk0_);        \
    } while (0)

#define STAB()                                                                \
    do {                                                                      \
        u16* ap_ = As + st_row * 72 + st_col;                                 \
        *(u16x8*)(ap_)             = ar0;                                     \
        *(u16x8*)(ap_ + 64 * 72)   = ar1;                                     \
        *(u16x8*)(ap_ + 128 * 72)  = ar2;                                     \
        *(u16x8*)(ap_ + 192 * 72)  = ar3;                                     \
        u16* bp_ = Bs + st_row * 72 + st_col;                                 \
        *(u16x8*)(bp_)             = br0;                                     \
        *(u16x8*)(bp_ + 64 * 72)   = br1;                                     \
    } while (0)

    LDAB(0);
    STAB();
    __syncthreads();

    const int nks = K >> 6;
    for (int ks = 0; ks < nks; ks++) {
        const bool more = (ks + 1 < nks);
        if (more) LDAB(ks + 1);
#pragma unroll
        for (int kk = 0; kk < 64; kk += 32) {
            u16x8 af[4], bfr[4];
#pragma unroll
            for (int i = 0; i < 4; i++)
                af[i] = *(const u16x8*)(As + (wr + i * 16 + r16) * 72 + kk + 8 * quad);
#pragma unroll
            for (int j = 0; j < 4; j++)
                bfr[j] = *(const u16x8*)(Bs + (wc + j * 16 + r16) * 72 + kk + 8 * quad);
#pragma unroll
            for (int i = 0; i < 4; i++)
#pragma unroll
                for (int j = 0; j < 4; j++)
                    acc[i][j] = mfma16(af[i], bfr[j], acc[i][j]);
        }
        __syncthreads();
        if (more) {
            STAB();
            __syncthreads();
        }
    }
#undef LDAB
#undef STAB

#pragma unroll
    for (int i = 0; i < 4; i++) {
#pragma unroll
        for (int j = 0; j < 4; j++) {
            const int gcol = wc + j * 16 + r16;
            const float bv = bias ? bias[blockIdx.y * 128 + gcol] : 0.f;
#pragma unroll
            for (int r = 0; r < 4; r++) {
                const long o = coff + (long)(wr + i * 16 + quad * 4 + r) * ldc + gcol;
                float v = acc[i][j][r] + bv;
                if (relu) v = fmaxf(v, 0.f);
                Cb[o] = f2bf(v);
            }
        }
    }
}

// --------------------------------------------- fused QKV/KV projection ----
template <int NSEG>
__global__ void __launch_bounds__(256) k_proj(
    const float* __restrict__ A,
    const float* __restrict__ W0, const float* __restrict__ W1,
    const float* __restrict__ W2,
    u16* __restrict__ C0, u16* __restrict__ C1, u16* __restrict__ C2)
{
    __shared__ __align__(16) u16 As[128 * 72];
    __shared__ __align__(16) u16 Bs[128 * 72];
    const int tid  = threadIdx.x;
    const int lane = tid & 63, wave = tid >> 6;
    const int r16  = lane & 15, quad = lane >> 4;
    const int wr   = (wave >> 1) * 64, wc = (wave & 1) * 64;
    const int seg = blockIdx.y >> 1, yy = blockIdx.y & 1, h = blockIdx.z;
    const float* W = (NSEG >= 3 && seg == 2) ? W2 : (seg == 1 ? W1 : W0);
    u16*         C = (NSEG >= 3 && seg == 2) ? C2 : (seg == 1 ? C1 : C0);
    const float* Ab = A + (long)blockIdx.x * 128 * 1024 + h * 256;
    const float* Bb = W + (long)h * 65536 + yy * 128 * 256;
    u16* Cp = C + (long)blockIdx.x * 128 * 1024 + h * 256 + yy * 128;

    f32x4 acc[4][4];
#pragma unroll
    for (int i = 0; i < 4; i++)
#pragma unroll
        for (int j = 0; j < 4; j++) acc[i][j] = f32x4{0.f, 0.f, 0.f, 0.f};

    const int st_row = tid >> 3, st_col = (tid & 7) * 8;

    for (int k0 = 0; k0 < 256; k0 += 64) {
#pragma unroll
        for (int r = 0; r < 4; r++) {
            const int row = st_row + 32 * r;
            *(u16x8*)(As + row * 72 + st_col) = ld8_f32(Ab + (long)row * 1024 + k0 + st_col);
            *(u16x8*)(Bs + row * 72 + st_col) = ld8_f32(Bb + (long)row * 256 + k0 + st_col);
        }
        __syncthreads();
#pragma unroll
        for (int kk = 0; kk < 64; kk += 32) {
            u16x8 af[4], bfr[4];
#pragma unroll
            for (int i = 0; i < 4; i++)
                af[i] = *(const u16x8*)(As + (wr + i * 16 + r16) * 72 + kk + 8 * quad);
#pragma unroll
            for (int j = 0; j < 4; j++)
                bfr[j] = *(const u16x8*)(Bs + (wc + j * 16 + r16) * 72 + kk + 8 * quad);
#pragma unroll
            for (int i = 0; i < 4; i++)
#pragma unroll
                for (int j = 0; j < 4; j++)
                    acc[i][j] = mfma16(af[i], bfr[j], acc[i][j]);
        }
        __syncthreads();
    }

#pragma unroll
    for (int i = 0; i < 4; i++)
#pragma unroll
        for (int j = 0; j < 4; j++)
#pragma unroll
            for (int r = 0; r < 4; r++)
                Cp[(long)(wr + i * 16 + quad * 4 + r) * 1024 + wc + j * 16 + r16] =
                    f2bf(acc[i][j][r]);
}

// ----------------------------------------------------- fused attention ----
// R15-verified core; R17/R18: ST_KV moved between softmax and PV so its
// vmcnt waits hide under PV issue instead of extending the barrier convoy.
template <int MASKED>
__global__ void __launch_bounds__(512, 2) k_attn(
    const u16* __restrict__ Q, const u16* __restrict__ Kg, const u16* __restrict__ Vt,
    u16* __restrict__ O, int T, float scale)
{
    const int D = 1024;
    __shared__ __align__(16) u16 Ks[2][64 * 264];
    __shared__ __align__(16) u16 VsT[2][256 * 72];
    __shared__ __align__(16) u16 Ps[8][16 * 72];
    const int tid = threadIdx.x, lane = tid & 63, wave = tid >> 6;
    const int r16 = lane & 15, quad = lane >> 4;

    const int fid = blockIdx.x;                      // grid 256, 1/CU
    const int swz = ((fid & 7) << 5) | (fid >> 3);   // bijective, 256%8==0
    const int grp = swz & 15, hh = (swz >> 4) & 3, bb = swz >> 6;

    int qr0, nkb, myMax;
    if (MASKED) {
        const int strip = (wave < 4) ? grp : (31 - grp);
        qr0   = strip * 64 + (wave & 3) * 16;
        myMax = strip;
        nkb   = 32 - grp;
    } else {
        qr0   = grp * 128 + wave * 16;
        myMax = 1 << 30;
        nkb   = T / 64;
    }

    const long base   = ((long)bb * T) * D + hh * 256;
    const long vtbase = ((long)(bb * 4 + hh) * 256) * 2048;

    u16x8 qf[8];
#pragma unroll
    for (int ks = 0; ks < 8; ks++)
        qf[ks] = *(const u16x8*)(Q + base + (long)(qr0 + r16) * D + ks * 32 + 8 * quad);

    f32x4 oacc[16];
#pragma unroll
    for (int nt = 0; nt < 16; nt++) oacc[nt] = f32x4{0.f, 0.f, 0.f, 0.f};
    f32x4 lacc = f32x4{0.f, 0.f, 0.f, 0.f};
    const u16x8 ones8 = {0x3F80, 0x3F80, 0x3F80, 0x3F80,
                         0x3F80, 0x3F80, 0x3F80, 0x3F80};   // bf16 1.0

    const int krow = tid >> 5, kcol = (tid & 31) * 8;
    const int vrow = tid >> 3, vcol = (tid & 7) * 8;

    const u16* kg = Kg + base;
    const u16* vg = Vt + vtbase + (long)vrow * 2048 + vcol;

    uint4 kr0, kr1, kr2, kr3, vr0, vr1, vr2, vr3;

#define LD_KV(KB)                                                          \
    do {                                                                   \
        const u16* kp_ = kg + ((long)(KB) * 64 + krow) * D + kcol;         \
        kr0 = *(const uint4*)(kp_);                                        \
        kr1 = *(const uint4*)(kp_ + 16 * D);                               \
        kr2 = *(const uint4*)(kp_ + 32 * D);                               \
        kr3 = *(const uint4*)(kp_ + 48 * D);                               \
        const u16* vp_ = vg + (KB) * 64;                                   \
        vr0 = *(const uint4*)(vp_);                                        \
        vr1 = *(const uint4*)(vp_ + 64 * 2048);                            \
        vr2 = *(const uint4*)(vp_ + 128 * 2048);                           \
        vr3 = *(const uint4*)(vp_ + 192 * 2048);                           \
    } while (0)

#define ST_KV(P)                                                           \
    do {                                                                   \
        u16* kq_ = Ks[P] + krow * 264 + kcol;                              \
        *(uint4*)(kq_)            = kr0;                                   \
        *(uint4*)(kq_ + 16 * 264) = kr1;                                   \
        *(uint4*)(kq_ + 32 * 264) = kr2;                                   \
        *(uint4*)(kq_ + 48 * 264) = kr3;                                   \
        u16* vq_ = VsT[P] + vrow * 72 + vcol;                              \
        *(uint4*)(vq_)            = vr0;                                   \
        *(uint4*)(vq_ + 64 * 72)  = vr1;                                   \
        *(uint4*)(vq_ + 128 * 72) = vr2;                                   \
        *(uint4*)(vq_ + 192 * 72) = vr3;                                   \
    } while (0)

    LD_KV(0);
    ST_KV(0);
    __syncthreads();

    u16* const pw = &Ps[wave][0];
    int p = 0;

    for (int kb = 0; kb < nkb; kb++) {
        const bool more = (kb + 1 < nkb);
        if (more) LD_KV(kb + 1);

        if (!MASKED || kb <= myMax) {        // wave-uniform predicate
            const u16* ks_ = Ks[p];
            const u16* vs_ = VsT[p];

            f32x4 s0 = f32x4{0.f,0.f,0.f,0.f}, s1 = f32x4{0.f,0.f,0.f,0.f};
            f32x4 s2 = f32x4{0.f,0.f,0.f,0.f}, s3 = f32x4{0.f,0.f,0.f,0.f};
            __builtin_amdgcn_s_setprio(1);
#pragma unroll
            for (int ks = 0; ks < 8; ks++) {
                const u16x8 a = qf[ks];
                const u16* kp = ks_ + r16 * 264 + ks * 32 + 8 * quad;
                s0 = mfma16(a, *(const u16x8*)(kp),            s0);
                s1 = mfma16(a, *(const u16x8*)(kp + 16 * 264), s1);
                s2 = mfma16(a, *(const u16x8*)(kp + 32 * 264), s2);
                s3 = mfma16(a, *(const u16x8*)(kp + 48 * 264), s3);
            }
            __builtin_amdgcn_s_setprio(0);

            const bool domask = MASKED && (kb == myMax);

#pragma unroll
            for (int r = 0; r < 4; r++) {
                float a0 = s0[r] * scale, a1 = s1[r] * scale;
                float a2 = s2[r] * scale, a3 = s3[r] * scale;
                if (domask) {
                    const int qi = qr0 + quad * 4 + r;
                    const int kb0 = kb * 64;
                    if (kb0 + r16 > qi)      a0 = -1e30f;
                    if (kb0 + 16 + r16 > qi) a1 = -1e30f;
                    if (kb0 + 32 + r16 > qi) a2 = -1e30f;
                    if (kb0 + 48 + r16 > qi) a3 = -1e30f;
                }
                const float p0 = __expf(fminf(a0, 30.f));
                const float p1 = __expf(fminf(a1, 30.f));
                const float p2 = __expf(fminf(a2, 30.f));
                const float p3 = __expf(fminf(a3, 30.f));
                u16* pr = pw + (quad * 4 + r) * 72 + r16;
                pr[0]  = f2bf(p0);
                pr[16] = f2bf(p1);
                pr[32] = f2bf(p2);
                pr[48] = f2bf(p3);
            }

            // stage next tile NOW: vmcnt waits hide under PV issue
            if (more) ST_KV(p ^ 1);

            const u16* pp = pw + r16 * 72 + 8 * quad;
            const u16x8 pfA = *(const u16x8*)(pp);
            const u16x8 pfB = *(const u16x8*)(pp + 32);
            __builtin_amdgcn_s_setprio(1);
            lacc = mfma16(pfA, ones8, lacc);
            lacc = mfma16(pfB, ones8, lacc);
#pragma unroll
            for (int nt = 0; nt < 16; nt++) {
                const u16* vp = vs_ + (nt * 16 + r16) * 72 + 8 * quad;
                oacc[nt] = mfma16(pfA, *(const u16x8*)(vp),      oacc[nt]);
                oacc[nt] = mfma16(pfB, *(const u16x8*)(vp + 32), oacc[nt]);
            }
            __builtin_amdgcn_s_setprio(0);
        } else if (more) {
            ST_KV(p ^ 1);                     // skipped-compute waves still stage
        }

        if (more) __syncthreads();
        p ^= 1;
    }
#undef LD_KV
#undef ST_KV

#pragma unroll
    for (int r = 0; r < 4; r++) lacc[r] = 1.f / lacc[r];
#pragma unroll
    for (int nt = 0; nt < 16; nt++)
#pragma unroll
        for (int r = 0; r < 4; r++)
            O[base + (long)(qr0 + quad * 4 + r) * D + nt * 16 + r16] =
                f2bf(oacc[nt][r] * lacc[r]);
}

// ----------------------------------------------------- add + layernorm ----
template <int XF32, int RF32>
__global__ void __launch_bounds__(256) k_addln(
    const void* __restrict__ Xp, const void* __restrict__ Rp,
    const float* __restrict__ G, const float* __restrict__ Bv,
    float* __restrict__ Yf, u16* __restrict__ Yb)
{
    const int tid = threadIdx.x;
    const long off = (long)blockIdx.x * 1024 + tid * 4;
    float v[4];
    if constexpr (XF32) {
        const float4 a = *(const float4*)((const float*)Xp + off);
        v[0] = a.x; v[1] = a.y; v[2] = a.z; v[3] = a.w;
    } else {
        const u16x4 a = *(const u16x4*)((const u16*)Xp + off);
        v[0] = bf2f(a[0]); v[1] = bf2f(a[1]); v[2] = bf2f(a[2]); v[3] = bf2f(a[3]);
    }
    if constexpr (RF32) {
        const float4 b = *(const float4*)((const float*)Rp + off);
        v[0] += b.x; v[1] += b.y; v[2] += b.z; v[3] += b.w;
    } else {
        const u16x4 b = *(const u16x4*)((const u16*)Rp + off);
        v[0] += bf2f(b[0]); v[1] += bf2f(b[1]); v[2] += bf2f(b[2]); v[3] += bf2f(b[3]);
    }
    float s1 = v[0] + v[1] + v[2] + v[3];
    float s2 = v[0]*v[0] + v[1]*v[1] + v[2]*v[2] + v[3]*v[3];
#pragma unroll
    for (int m = 1; m < 64; m <<= 1) { s1 += __shfl_xor(s1, m); s2 += __shfl_xor(s2, m); }
    __shared__ float red[8];
    if ((tid & 63) == 0) { red[(tid >> 6) * 2] = s1; red[(tid >> 6) * 2 + 1] = s2; }
    __syncthreads();
    s1 = red[0] + red[2] + red[4] + red[6];
    s2 = red[1] + red[3] + red[5] + red[7];
    const float mean = s1 * (1.f / 1024.f);
    const float rstd = rsqrtf(s2 * (1.f / 1024.f) - mean * mean + 1e-5f);
    const float4 g  = *(const float4*)(G + tid * 4);
    const float4 be = *(const float4*)(Bv + tid * 4);
    const float o0 = (v[0] - mean) * rstd * g.x + be.x;
    const float o1 = (v[1] - mean) * rstd * g.y + be.y;
    const float o2 = (v[2] - mean) * rstd * g.z + be.z;
    const float o3 = (v[3] - mean) * rstd * g.w + be.w;
    if (Yf) { float4 of = {o0, o1, o2, o3}; *(float4*)(Yf + off) = of; }
    if (Yb) { u16x4 ob = {f2bf(o0), f2bf(o1), f2bf(o2), f2bf(o3)}; *(u16x4*)(Yb + off) = ob; }
}

// ----------------------------- per-(b,h) head transpose (1 or 2 sources) ----
__global__ void __launch_bounds__(256) k_transpose2(
    const u16* __restrict__ X0, u16* __restrict__ Y0,
    const u16* __restrict__ X1, u16* __restrict__ Y1)
{
    __shared__ u16 tile[32][33];
    const int tx = threadIdx.x & 31, ty = threadIdx.x >> 5;
    const int zz = blockIdx.z;
    const int bh = zz & 15;
    const u16* Xin = (zz < 16) ? X0 : X1;
    u16*       Y   = (zz < 16) ? Y0 : Y1;
    const int t0 = blockIdx.x * 32, e0 = blockIdx.y * 32;
    const int b = bh >> 2, h = bh & 3;
#pragma unroll
    for (int i = 0; i < 4; i++)
        tile[ty + 8 * i][tx] =
            Xin[((long)(b * 2048 + t0 + ty + 8 * i)) * 1024 + h * 256 + e0 + tx];
    __syncthreads();
#pragma unroll
    for (int i = 0; i < 4; i++)
        Y[((long)bh * 256 + e0 + ty + 8 * i) * 2048 + t0 + tx] = tile[tx][ty + 8 * i];
}

// ------------------------------------------------------------- driver ----
#define GEMM(AF, BF, Aptr, lda, Bptr, ldb, pCf, pCb, ldc, bias, relu, accum, alpha, \
             M, N, K, Z, Hdiv, sAb, sAh, sBb, sBh, sCb, sCh)                        \
    k_gemm_bt<AF, BF><<<dim3((M) / 128, (N) / 128, (Z)), dim3(256), 0, stream>>>(   \
        (const void*)(Aptr), (lda), (const void*)(Bptr), (ldb), (pCf), (pCb),       \
        (ldc), (bias), (relu), (accum), (alpha), (K), (Hdiv),                       \
        (long)(sAb), (long)(sAh), (long)(sBb), (long)(sBh), (long)(sCb), (long)(sCh))

extern "C" void kernel_launch(void* const* d_in, const int* in_sizes, int n_in,
                              void* d_out, int out_size, void* d_ws, size_t ws_size,
                              hipStream_t stream)
{
    const int Bn = 4, T = 2048, D = 1024, H = 4, DH = 256;
    const long BTD = (long)Bn * T * D;
    const long MB = 1024 * 1024;

    const float* ctx = (const float*)d_in[0];
    const float* X   = (const float*)d_in[1];
    const float* Wh[9]; for (int i = 0; i < 9; i++) Wh[i] = (const float*)d_in[2 + i];
    const float* dec_w1 = (const float*)d_in[11]; const float* dec_b1 = (const float*)d_in[12];
    const float* dec_w2 = (const float*)d_in[13]; const float* dec_b2 = (const float*)d_in[14];
    const float* enc_w1 = (const float*)d_in[15]; const float* enc_b1 = (const float*)d_in[16];
    const float* enc_w2 = (const float*)d_in[17]; const float* enc_b2 = (const float*)d_in[18];
    const float* ln[10]; for (int i = 0; i < 10; i++) ln[i] = (const float*)d_in[19 + i];
    (void)in_sizes; (void)n_in; (void)out_size; (void)ws_size;

    float* outC = (float*)d_out;
    float* outY = (float*)d_out + BTD;

    // ---- workspace pool (98.3 MB, proven safe) ----
    char* w = (char*)d_ws;
    u16*   qb   = (u16*)(w);
    u16*   kb   = (u16*)(w + 16 * MB);
    u16*   vb   = (u16*)(w + 32 * MB);
    u16*   tmpB = (u16*)(w + 48 * MB);
    u16*   hb64 = (u16*)(w);                  // 64 MB FFN hidden (full M)
    u16*   Kt2  = (u16*)(w + 32 * MB);        // cross K^T
    u16*   crossO= (u16*)(w + 32 * MB);       // cross attn out (after Kt2 dead)
    u16*   Vt2  = (u16*)(w + 48 * MB);        // cross V^T
    u16*   Nm   = (u16*)(w + 64 * MB);
    u16*   x1b  = (u16*)(w + 66 * MB);
    u16*   t2b  = (u16*)(w + 82 * MB);        // c1 / x2

    u16* w1o = (u16*)outY;                    //  8 MB bf16 w1 (outY scratch)
    u16* w2o = w1o + 4194304;                 //  8 MB bf16 w2
    u16* foutE = w1o + 8388608;               // 16 MB bf16 enc FFN out
    u16* foutD = x1b;                         // 16 MB bf16 dec FFN out

    // ---- 1) decoder masked self-attn: x1 = LN(X + attn(X)) ----
    k_proj<3><<<dim3(64, 6, 4), dim3(256), 0, stream>>>(
        X, Wh[0], Wh[1], Wh[2], qb, kb, vb);
    k_transpose2<<<dim3(T / 32, DH / 32, 16), dim3(256), 0, stream>>>(
        vb, tmpB, nullptr, nullptr);
    k_attn<1><<<dim3(256), dim3(512), 0, stream>>>(qb, kb, tmpB, vb, T, 0.0625f);
    k_addln<1, 0><<<dim3(Bn * T), dim3(256), 0, stream>>>(X, vb, ln[0], ln[1], nullptr, x1b);

    // ---- 2) encoder self-attn: c1 = LN(ctx + attn(ctx)) ----
    k_proj<3><<<dim3(64, 6, 4), dim3(256), 0, stream>>>(
        ctx, Wh[6], Wh[7], Wh[8], qb, kb, vb);
    k_transpose2<<<dim3(T / 32, DH / 32, 16), dim3(256), 0, stream>>>(
        vb, tmpB, nullptr, nullptr);
    k_attn<0><<<dim3(256), dim3(512), 0, stream>>>(qb, kb, tmpB, vb, T, 0.0625f);
    k_addln<1, 0><<<dim3(Bn * T), dim3(256), 0, stream>>>(ctx, vb, ln[6], ln[7], nullptr, t2b);

    // ---- 3) encoder FFN (full-M; GEMM1 256x128, GEMM2 128^2): -> outC ----
    k_cast<<<dim3(4096), dim3(256), 0, stream>>>(enc_w1, w1o, 1048576);
    k_cast<<<dim3(4096), dim3(256), 0, stream>>>(enc_w2, w2o, 1048576);
    k_gemm256<<<dim3(32, 32), dim3(512), 0, stream>>>(
        t2b, D, w1o, D, hb64, 4096, enc_b1, 1, 1024);
    GEMM(0, 0, hb64, 4096, w2o, 4096, nullptr, foutE, 1024, enc_b2, 0, 0, 1.f,
         Bn * T, 1024, 4096, 1, 1, 0, 0, 0, 0, 0, 0);
    k_addln<0, 0><<<dim3(Bn * T), dim3(256), 0, stream>>>(
        t2b, foutE, ln[8], ln[9], outC, nullptr);

    // ---- 4) cross attention (no softmax): o = q (K^T V)^T / 16 ----
    GEMM(0, 1, x1b, D, Wh[3], DH, nullptr, qb, D, nullptr, 0, 0, 1.f,
         Bn * T, DH, DH, H, H, 0, DH, 0, DH * DH, 0, DH);
    k_proj<2><<<dim3(64, 4, 4), dim3(256), 0, stream>>>(
        outC, Wh[4], Wh[5], nullptr, kb, t2b, nullptr);
    k_transpose2<<<dim3(T / 32, DH / 32, 32), dim3(256), 0, stream>>>(
        kb, Kt2, t2b, Vt2);
    GEMM(0, 0, Vt2, T, Kt2, T, nullptr, Nm, DH, nullptr, 0, 0, 1.f,
         DH, DH, T, Bn * H, Bn * H, 0, (long)DH * T, 0, (long)DH * T, 0, DH * DH);
    GEMM(0, 0, qb, D, Nm, DH, nullptr, crossO, D, nullptr, 0, 0, 0.0625f,
         T, DH, DH, Bn * H, H, (long)T * D, DH, (long)H * DH * DH, DH * DH,
         (long)T * D, DH);
    k_addln<0, 0><<<dim3(Bn * T), dim3(256), 0, stream>>>(x1b, crossO, ln[2], ln[3], nullptr, t2b);

    // ---- 5) decoder FFN (full-M): -> outY ----
    k_cast<<<dim3(4096), dim3(256), 0, stream>>>(dec_w1, w1o, 1048576);
    k_cast<<<dim3(4096), dim3(256), 0, stream>>>(dec_w2, w2o, 1048576);
    k_gemm256<<<dim3(32, 32), dim3(512), 0, stream>>>(
        t2b, D, w1o, D, hb64, 4096, dec_b1, 1, 1024);
    GEMM(0, 0, hb64, 4096, w2o, 4096, nullptr, foutD, 1024, dec_b2, 0, 0, 1.f,
         Bn * T, 1024, 4096, 1, 1, 0, 0, 0, 0, 0, 0);
    k_addln<0, 0><<<dim3(Bn * T), dim3(256), 0, stream>>>(
        t2b, foutD, ln[4], ln[5], outY, nullptr);
}

// Round 19
// 817.917 us; speedup vs baseline: 1.0398x; 1.0398x over previous
//
#include <hip/hip_runtime.h>
#include <hip/hip_bf16.h>

typedef unsigned short u16;
typedef __bf16 bf16x8 __attribute__((ext_vector_type(8)));
typedef unsigned short u16x8 __attribute__((ext_vector_type(8)));
typedef unsigned short u16x4 __attribute__((ext_vector_type(4)));
typedef float f32x4 __attribute__((ext_vector_type(4)));

#define DI static __device__ __forceinline__

DI u16 f2bf(float f) {
    unsigned u = __builtin_bit_cast(unsigned, f);
    u += 0x7FFFu + ((u >> 16) & 1u);   // round-to-nearest-even
    return (u16)(u >> 16);
}
DI float bf2f(u16 u) {
    unsigned x = ((unsigned)u) << 16;
    return __builtin_bit_cast(float, x);
}
DI u16x8 ld8_f32(const float* __restrict__ p) {
    const float4 a = *(const float4*)p;
    const float4 b = *(const float4*)(p + 4);
    u16x8 r = { f2bf(a.x), f2bf(a.y), f2bf(a.z), f2bf(a.w),
                f2bf(b.x), f2bf(b.y), f2bf(b.z), f2bf(b.w) };
    return r;
}
DI f32x4 mfma16(u16x8 a, u16x8 b, f32x4 c) {
    return __builtin_amdgcn_mfma_f32_16x16x32_bf16(
        __builtin_bit_cast(bf16x8, a), __builtin_bit_cast(bf16x8, b), c, 0, 0, 0);
}

// ---------------------------------------------------------------- cast ----
__global__ void __launch_bounds__(256) k_cast(const float* __restrict__ in,
                                              u16* __restrict__ out, long n4) {
    long i = (long)blockIdx.x * 256 + threadIdx.x;
    if (i >= n4) return;
    const float4 v = *(const float4*)(in + i * 4);
    u16x4 o = { f2bf(v.x), f2bf(v.y), f2bf(v.z), f2bf(v.w) };
    *(u16x4*)(out + i * 4) = o;
}

// ---------------------------------------------------------------- GEMM ----
// R11/R12-verified best 128x128: single-buffer padded LDS (stride 72),
// named-reg prefetch, 2 barriers/K-step. Rejected alternatives (all A/B'd
// slower): gload_lds (R7/R10), dbuf (R13), counted-vmcnt pipeline (R14),
// 256x128 8-wave tile (R18, +25us).
template <int AF32, int BF32>
__global__ void __launch_bounds__(256, 2) k_gemm_bt(
    const void* __restrict__ Ap, long lda,
    const void* __restrict__ Bp, long ldb,
    float* __restrict__ Cf, u16* __restrict__ Cb, long ldc,
    const float* __restrict__ bias, int relu, int accum, float alpha, int K,
    int Hdiv, long sAb, long sAh, long sBb, long sBh, long sCb, long sCh)
{
    __shared__ __align__(16) u16 As[128 * 72];
    __shared__ __align__(16) u16 Bs[128 * 72];
    const int tid  = threadIdx.x;
    const int lane = tid & 63, wave = tid >> 6;
    const int r16  = lane & 15, quad = lane >> 4;
    const int wr   = (wave >> 1) * 64, wc = (wave & 1) * 64;
    const int zb = blockIdx.z / Hdiv, zh = blockIdx.z % Hdiv;
    const long aoff = (long)zb * sAb + (long)zh * sAh + (long)blockIdx.x * 128 * lda;
    const long boff = (long)zb * sBb + (long)zh * sBh + (long)blockIdx.y * 128 * ldb;
    const u16*   A16 = (const u16*)Ap + aoff;
    const float* A32 = (const float*)Ap + aoff;
    const u16*   B16 = (const u16*)Bp + boff;
    const float* B32 = (const float*)Bp + boff;
    const long coff = (long)zb * sCb + (long)zh * sCh +
                      (long)blockIdx.x * 128 * ldc + (long)blockIdx.y * 128;

    f32x4 acc[4][4];
#pragma unroll
    for (int i = 0; i < 4; i++)
#pragma unroll
        for (int j = 0; j < 4; j++) acc[i][j] = f32x4{0.f, 0.f, 0.f, 0.f};

    const int st_row = tid >> 3;
    const int st_col = (tid & 7) * 8;

    u16x8 ar0, ar1, ar2, ar3, br0, br1, br2, br3;

#define LDAB(KS)                                                              \
    do {                                                                      \
        const long kk0_ = (long)(KS) * 64 + st_col;                           \
        if constexpr (AF32) {                                                 \
            ar0 = ld8_f32(A32 + (long)(st_row)      * lda + kk0_);            \
            ar1 = ld8_f32(A32 + (long)(st_row + 32) * lda + kk0_);            \
            ar2 = ld8_f32(A32 + (long)(st_row + 64) * lda + kk0_);            \
            ar3 = ld8_f32(A32 + (long)(st_row + 96) * lda + kk0_);            \
        } else {                                                              \
            ar0 = *(const u16x8*)(A16 + (long)(st_row)      * lda + kk0_);    \
            ar1 = *(const u16x8*)(A16 + (long)(st_row + 32) * lda + kk0_);    \
            ar2 = *(const u16x8*)(A16 + (long)(st_row + 64) * lda + kk0_);    \
            ar3 = *(const u16x8*)(A16 + (long)(st_row + 96) * lda + kk0_);    \
        }                                                                     \
        if constexpr (BF32) {                                                 \
            br0 = ld8_f32(B32 + (long)(st_row)      * ldb + kk0_);            \
            br1 = ld8_f32(B32 + (long)(st_row + 32) * ldb + kk0_);            \
            br2 = ld8_f32(B32 + (long)(st_row + 64) * ldb + kk0_);            \
            br3 = ld8_f32(B32 + (long)(st_row + 96) * ldb + kk0_);            \
        } else {                                                              \
            br0 = *(const u16x8*)(B16 + (long)(st_row)      * ldb + kk0_);    \
            br1 = *(const u16x8*)(B16 + (long)(st_row + 32) * ldb + kk0_);    \
            br2 = *(const u16x8*)(B16 + (long)(st_row + 64) * ldb + kk0_);    \
            br3 = *(const u16x8*)(B16 + (long)(st_row + 96) * ldb + kk0_);    \
        }                                                                     \
    } while (0)

#define STAB()                                                                \
    do {                                                                      \
        u16* ap_ = As + st_row * 72 + st_col;                                 \
        *(u16x8*)(ap_)            = ar0;                                      \
        *(u16x8*)(ap_ + 32 * 72)  = ar1;                                      \
        *(u16x8*)(ap_ + 64 * 72)  = ar2;                                      \
        *(u16x8*)(ap_ + 96 * 72)  = ar3;                                      \
        u16* bp_ = Bs + st_row * 72 + st_col;                                 \
        *(u16x8*)(bp_)            = br0;                                      \
        *(u16x8*)(bp_ + 32 * 72)  = br1;                                      \
        *(u16x8*)(bp_ + 64 * 72)  = br2;                                      \
        *(u16x8*)(bp_ + 96 * 72)  = br3;                                      \
    } while (0)

    LDAB(0);
    STAB();
    __syncthreads();

    const int nks = K >> 6;
    for (int ks = 0; ks < nks; ks++) {
        const bool more = (ks + 1 < nks);
        if (more) LDAB(ks + 1);
#pragma unroll
        for (int kk = 0; kk < 64; kk += 32) {
            u16x8 af[4], bfr[4];
#pragma unroll
            for (int i = 0; i < 4; i++)
                af[i] = *(const u16x8*)(As + (wr + i * 16 + r16) * 72 + kk + 8 * quad);
#pragma unroll
            for (int j = 0; j < 4; j++)
                bfr[j] = *(const u16x8*)(Bs + (wc + j * 16 + r16) * 72 + kk + 8 * quad);
#pragma unroll
            for (int i = 0; i < 4; i++)
#pragma unroll
                for (int j = 0; j < 4; j++)
                    acc[i][j] = mfma16(af[i], bfr[j], acc[i][j]);
        }
        __syncthreads();
        if (more) {
            STAB();
            __syncthreads();
        }
    }
#undef LDAB
#undef STAB

#pragma unroll
    for (int i = 0; i < 4; i++) {
#pragma unroll
        for (int j = 0; j < 4; j++) {
            const int gcol = wc + j * 16 + r16;
            const float bv = bias ? bias[blockIdx.y * 128 + gcol] : 0.f;
#pragma unroll
            for (int r = 0; r < 4; r++) {
                const long o = coff + (long)(wr + i * 16 + quad * 4 + r) * ldc + gcol;
                float v = acc[i][j][r] * alpha + bv;
                if (accum) v += Cf[o];
                if (relu) v = fmaxf(v, 0.f);
                if (Cf) Cf[o] = v;
                if (Cb) Cb[o] = f2bf(v);
            }
        }
    }
}

// --------------------------------------------- fused QKV/KV projection ----
template <int NSEG>
__global__ void __launch_bounds__(256) k_proj(
    const float* __restrict__ A,
    const float* __restrict__ W0, const float* __restrict__ W1,
    const float* __restrict__ W2,
    u16* __restrict__ C0, u16* __restrict__ C1, u16* __restrict__ C2)
{
    __shared__ __align__(16) u16 As[128 * 72];
    __shared__ __align__(16) u16 Bs[128 * 72];
    const int tid  = threadIdx.x;
    const int lane = tid & 63, wave = tid >> 6;
    const int r16  = lane & 15, quad = lane >> 4;
    const int wr   = (wave >> 1) * 64, wc = (wave & 1) * 64;
    const int seg = blockIdx.y >> 1, yy = blockIdx.y & 1, h = blockIdx.z;
    const float* W = (NSEG >= 3 && seg == 2) ? W2 : (seg == 1 ? W1 : W0);
    u16*         C = (NSEG >= 3 && seg == 2) ? C2 : (seg == 1 ? C1 : C0);
    const float* Ab = A + (long)blockIdx.x * 128 * 1024 + h * 256;
    const float* Bb = W + (long)h * 65536 + yy * 128 * 256;
    u16* Cp = C + (long)blockIdx.x * 128 * 1024 + h * 256 + yy * 128;

    f32x4 acc[4][4];
#pragma unroll
    for (int i = 0; i < 4; i++)
#pragma unroll
        for (int j = 0; j < 4; j++) acc[i][j] = f32x4{0.f, 0.f, 0.f, 0.f};

    const int st_row = tid >> 3, st_col = (tid & 7) * 8;

    for (int k0 = 0; k0 < 256; k0 += 64) {
#pragma unroll
        for (int r = 0; r < 4; r++) {
            const int row = st_row + 32 * r;
            *(u16x8*)(As + row * 72 + st_col) = ld8_f32(Ab + (long)row * 1024 + k0 + st_col);
            *(u16x8*)(Bs + row * 72 + st_col) = ld8_f32(Bb + (long)row * 256 + k0 + st_col);
        }
        __syncthreads();
#pragma unroll
        for (int kk = 0; kk < 64; kk += 32) {
            u16x8 af[4], bfr[4];
#pragma unroll
            for (int i = 0; i < 4; i++)
                af[i] = *(const u16x8*)(As + (wr + i * 16 + r16) * 72 + kk + 8 * quad);
#pragma unroll
            for (int j = 0; j < 4; j++)
                bfr[j] = *(const u16x8*)(Bs + (wc + j * 16 + r16) * 72 + kk + 8 * quad);
#pragma unroll
            for (int i = 0; i < 4; i++)
#pragma unroll
                for (int j = 0; j < 4; j++)
                    acc[i][j] = mfma16(af[i], bfr[j], acc[i][j]);
        }
        __syncthreads();
    }

#pragma unroll
    for (int i = 0; i < 4; i++)
#pragma unroll
        for (int j = 0; j < 4; j++)
#pragma unroll
            for (int r = 0; r < 4; r++)
                Cp[(long)(wr + i * 16 + quad * 4 + r) * 1024 + wc + j * 16 + r16] =
                    f2bf(acc[i][j][r]);
}

// ----------------------------------------------------- fused attention ----
// R15/R16-verified: dbuf K/V, ONE barrier/tile, ST_KV after PV (R18's
// pre-PV reorder cost +3us/dispatch -- reverted), softmax-free-reduction,
// matrix-pipe denominator, setprio; masked path pairs strips (j, 31-j).
template <int MASKED>
__global__ void __launch_bounds__(512, 2) k_attn(
    const u16* __restrict__ Q, const u16* __restrict__ Kg, const u16* __restrict__ Vt,
    u16* __restrict__ O, int T, float scale)
{
    const int D = 1024;
    __shared__ __align__(16) u16 Ks[2][64 * 264];
    __shared__ __align__(16) u16 VsT[2][256 * 72];
    __shared__ __align__(16) u16 Ps[8][16 * 72];
    const int tid = threadIdx.x, lane = tid & 63, wave = tid >> 6;
    const int r16 = lane & 15, quad = lane >> 4;

    const int fid = blockIdx.x;                      // grid 256, 1/CU
    const int swz = ((fid & 7) << 5) | (fid >> 3);   // bijective, 256%8==0
    const int grp = swz & 15, hh = (swz >> 4) & 3, bb = swz >> 6;

    int qr0, nkb, myMax;
    if (MASKED) {
        const int strip = (wave < 4) ? grp : (31 - grp);
        qr0   = strip * 64 + (wave & 3) * 16;
        myMax = strip;
        nkb   = 32 - grp;
    } else {
        qr0   = grp * 128 + wave * 16;
        myMax = 1 << 30;
        nkb   = T / 64;
    }

    const long base   = ((long)bb * T) * D + hh * 256;
    const long vtbase = ((long)(bb * 4 + hh) * 256) * 2048;

    u16x8 qf[8];
#pragma unroll
    for (int ks = 0; ks < 8; ks++)
        qf[ks] = *(const u16x8*)(Q + base + (long)(qr0 + r16) * D + ks * 32 + 8 * quad);

    f32x4 oacc[16];
#pragma unroll
    for (int nt = 0; nt < 16; nt++) oacc[nt] = f32x4{0.f, 0.f, 0.f, 0.f};
    f32x4 lacc = f32x4{0.f, 0.f, 0.f, 0.f};
    const u16x8 ones8 = {0x3F80, 0x3F80, 0x3F80, 0x3F80,
                         0x3F80, 0x3F80, 0x3F80, 0x3F80};   // bf16 1.0

    const int krow = tid >> 5, kcol = (tid & 31) * 8;
    const int vrow = tid >> 3, vcol = (tid & 7) * 8;

    const u16* kg = Kg + base;
    const u16* vg = Vt + vtbase + (long)vrow * 2048 + vcol;

    uint4 kr0, kr1, kr2, kr3, vr0, vr1, vr2, vr3;

#define LD_KV(KB)                                                          \
    do {                                                                   \
        const u16* kp_ = kg + ((long)(KB) * 64 + krow) * D + kcol;         \
        kr0 = *(const uint4*)(kp_);                                        \
        kr1 = *(const uint4*)(kp_ + 16 * D);                               \
        kr2 = *(const uint4*)(kp_ + 32 * D);                               \
        kr3 = *(const uint4*)(kp_ + 48 * D);                               \
        const u16* vp_ = vg + (KB) * 64;                                   \
        vr0 = *(const uint4*)(vp_);                                        \
        vr1 = *(const uint4*)(vp_ + 64 * 2048);                            \
        vr2 = *(const uint4*)(vp_ + 128 * 2048);                           \
        vr3 = *(const uint4*)(vp_ + 192 * 2048);                           \
    } while (0)

#define ST_KV(P)                                                           \
    do {                                                                   \
        u16* kq_ = Ks[P] + krow * 264 + kcol;                              \
        *(uint4*)(kq_)            = kr0;                                   \
        *(uint4*)(kq_ + 16 * 264) = kr1;                                   \
        *(uint4*)(kq_ + 32 * 264) = kr2;                                   \
        *(uint4*)(kq_ + 48 * 264) = kr3;                                   \
        u16* vq_ = VsT[P] + vrow * 72 + vcol;                              \
        *(uint4*)(vq_)            = vr0;                                   \
        *(uint4*)(vq_ + 64 * 72)  = vr1;                                   \
        *(uint4*)(vq_ + 128 * 72) = vr2;                                   \
        *(uint4*)(vq_ + 192 * 72) = vr3;                                   \
    } while (0)

    LD_KV(0);
    ST_KV(0);
    __syncthreads();

    u16* const pw = &Ps[wave][0];
    int p = 0;

    for (int kb = 0; kb < nkb; kb++) {
        const bool more = (kb + 1 < nkb);
        if (more) LD_KV(kb + 1);

        if (!MASKED || kb <= myMax) {        // wave-uniform predicate
            const u16* ks_ = Ks[p];
            const u16* vs_ = VsT[p];

            f32x4 s0 = f32x4{0.f,0.f,0.f,0.f}, s1 = f32x4{0.f,0.f,0.f,0.f};
            f32x4 s2 = f32x4{0.f,0.f,0.f,0.f}, s3 = f32x4{0.f,0.f,0.f,0.f};
            __builtin_amdgcn_s_setprio(1);
#pragma unroll
            for (int ks = 0; ks < 8; ks++) {
                const u16x8 a = qf[ks];
                const u16* kp = ks_ + r16 * 264 + ks * 32 + 8 * quad;
                s0 = mfma16(a, *(const u16x8*)(kp),            s0);
                s1 = mfma16(a, *(const u16x8*)(kp + 16 * 264), s1);
                s2 = mfma16(a, *(const u16x8*)(kp + 32 * 264), s2);
                s3 = mfma16(a, *(const u16x8*)(kp + 48 * 264), s3);
            }
            __builtin_amdgcn_s_setprio(0);

            const bool domask = MASKED && (kb == myMax);

#pragma unroll
            for (int r = 0; r < 4; r++) {
                float a0 = s0[r] * scale, a1 = s1[r] * scale;
                float a2 = s2[r] * scale, a3 = s3[r] * scale;
                if (domask) {
                    const int qi = qr0 + quad * 4 + r;
                    const int kb0 = kb * 64;
                    if (kb0 + r16 > qi)      a0 = -1e30f;
                    if (kb0 + 16 + r16 > qi) a1 = -1e30f;
                    if (kb0 + 32 + r16 > qi) a2 = -1e30f;
                    if (kb0 + 48 + r16 > qi) a3 = -1e30f;
                }
                const float p0 = __expf(fminf(a0, 30.f));
                const float p1 = __expf(fminf(a1, 30.f));
                const float p2 = __expf(fminf(a2, 30.f));
                const float p3 = __expf(fminf(a3, 30.f));
                u16* pr = pw + (quad * 4 + r) * 72 + r16;
                pr[0]  = f2bf(p0);
                pr[16] = f2bf(p1);
                pr[32] = f2bf(p2);
                pr[48] = f2bf(p3);
            }

            const u16* pp = pw + r16 * 72 + 8 * quad;
            const u16x8 pfA = *(const u16x8*)(pp);
            const u16x8 pfB = *(const u16x8*)(pp + 32);
            __builtin_amdgcn_s_setprio(1);
            lacc = mfma16(pfA, ones8, lacc);
            lacc = mfma16(pfB, ones8, lacc);
#pragma unroll
            for (int nt = 0; nt < 16; nt++) {
                const u16* vp = vs_ + (nt * 16 + r16) * 72 + 8 * quad;
                oacc[nt] = mfma16(pfA, *(const u16x8*)(vp),      oacc[nt]);
                oacc[nt] = mfma16(pfB, *(const u16x8*)(vp + 32), oacc[nt]);
            }
            __builtin_amdgcn_s_setprio(0);
        }

        if (more) {
            ST_KV(p ^ 1);         // post-PV slot (R15/R16-proven)
            __syncthreads();      // ONE barrier per tile
        }
        p ^= 1;
    }
#undef LD_KV
#undef ST_KV

#pragma unroll
    for (int r = 0; r < 4; r++) lacc[r] = 1.f / lacc[r];
#pragma unroll
    for (int nt = 0; nt < 16; nt++)
#pragma unroll
        for (int r = 0; r < 4; r++)
            O[base + (long)(qr0 + quad * 4 + r) * D + nt * 16 + r16] =
                f2bf(oacc[nt][r] * lacc[r]);
}

// ----------------------------------------------------- add + layernorm ----
template <int XF32, int RF32>
__global__ void __launch_bounds__(256) k_addln(
    const void* __restrict__ Xp, const void* __restrict__ Rp,
    const float* __restrict__ G, const float* __restrict__ Bv,
    float* __restrict__ Yf, u16* __restrict__ Yb)
{
    const int tid = threadIdx.x;
    const long off = (long)blockIdx.x * 1024 + tid * 4;
    float v[4];
    if constexpr (XF32) {
        const float4 a = *(const float4*)((const float*)Xp + off);
        v[0] = a.x; v[1] = a.y; v[2] = a.z; v[3] = a.w;
    } else {
        const u16x4 a = *(const u16x4*)((const u16*)Xp + off);
        v[0] = bf2f(a[0]); v[1] = bf2f(a[1]); v[2] = bf2f(a[2]); v[3] = bf2f(a[3]);
    }
    if constexpr (RF32) {
        const float4 b = *(const float4*)((const float*)Rp + off);
        v[0] += b.x; v[1] += b.y; v[2] += b.z; v[3] += b.w;
    } else {
        const u16x4 b = *(const u16x4*)((const u16*)Rp + off);
        v[0] += bf2f(b[0]); v[1] += bf2f(b[1]); v[2] += bf2f(b[2]); v[3] += bf2f(b[3]);
    }
    float s1 = v[0] + v[1] + v[2] + v[3];
    float s2 = v[0]*v[0] + v[1]*v[1] + v[2]*v[2] + v[3]*v[3];
#pragma unroll
    for (int m = 1; m < 64; m <<= 1) { s1 += __shfl_xor(s1, m); s2 += __shfl_xor(s2, m); }
    __shared__ float red[8];
    if ((tid & 63) == 0) { red[(tid >> 6) * 2] = s1; red[(tid >> 6) * 2 + 1] = s2; }
    __syncthreads();
    s1 = red[0] + red[2] + red[4] + red[6];
    s2 = red[1] + red[3] + red[5] + red[7];
    const float mean = s1 * (1.f / 1024.f);
    const float rstd = rsqrtf(s2 * (1.f / 1024.f) - mean * mean + 1e-5f);
    const float4 g  = *(const float4*)(G + tid * 4);
    const float4 be = *(const float4*)(Bv + tid * 4);
    const float o0 = (v[0] - mean) * rstd * g.x + be.x;
    const float o1 = (v[1] - mean) * rstd * g.y + be.y;
    const float o2 = (v[2] - mean) * rstd * g.z + be.z;
    const float o3 = (v[3] - mean) * rstd * g.w + be.w;
    if (Yf) { float4 of = {o0, o1, o2, o3}; *(float4*)(Yf + off) = of; }
    if (Yb) { u16x4 ob = {f2bf(o0), f2bf(o1), f2bf(o2), f2bf(o3)}; *(u16x4*)(Yb + off) = ob; }
}

// ----------------------------- per-(b,h) head transpose (1 or 2 sources) ----
__global__ void __launch_bounds__(256) k_transpose2(
    const u16* __restrict__ X0, u16* __restrict__ Y0,
    const u16* __restrict__ X1, u16* __restrict__ Y1)
{
    __shared__ u16 tile[32][33];
    const int tx = threadIdx.x & 31, ty = threadIdx.x >> 5;
    const int zz = blockIdx.z;
    const int bh = zz & 15;
    const u16* Xin = (zz < 16) ? X0 : X1;
    u16*       Y   = (zz < 16) ? Y0 : Y1;
    const int t0 = blockIdx.x * 32, e0 = blockIdx.y * 32;
    const int b = bh >> 2, h = bh & 3;
#pragma unroll
    for (int i = 0; i < 4; i++)
        tile[ty + 8 * i][tx] =
            Xin[((long)(b * 2048 + t0 + ty + 8 * i)) * 1024 + h * 256 + e0 + tx];
    __syncthreads();
#pragma unroll
    for (int i = 0; i < 4; i++)
        Y[((long)bh * 256 + e0 + ty + 8 * i) * 2048 + t0 + tx] = tile[tx][ty + 8 * i];
}

// ------------------------------------------------------------- driver ----
#define GEMM(AF, BF, Aptr, lda, Bptr, ldb, pCf, pCb, ldc, bias, relu, accum, alpha, \
             M, N, K, Z, Hdiv, sAb, sAh, sBb, sBh, sCb, sCh)                        \
    k_gemm_bt<AF, BF><<<dim3((M) / 128, (N) / 128, (Z)), dim3(256), 0, stream>>>(   \
        (const void*)(Aptr), (lda), (const void*)(Bptr), (ldb), (pCf), (pCb),       \
        (ldc), (bias), (relu), (accum), (alpha), (K), (Hdiv),                       \
        (long)(sAb), (long)(sAh), (long)(sBb), (long)(sBh), (long)(sCb), (long)(sCh))

extern "C" void kernel_launch(void* const* d_in, const int* in_sizes, int n_in,
                              void* d_out, int out_size, void* d_ws, size_t ws_size,
                              hipStream_t stream)
{
    const int Bn = 4, T = 2048, D = 1024, H = 4, DH = 256;
    const long BTD = (long)Bn * T * D;
    const long MB = 1024 * 1024;

    const float* ctx = (const float*)d_in[0];
    const float* X   = (const float*)d_in[1];
    const float* Wh[9]; for (int i = 0; i < 9; i++) Wh[i] = (const float*)d_in[2 + i];
    const float* dec_w1 = (const float*)d_in[11]; const float* dec_b1 = (const float*)d_in[12];
    const float* dec_w2 = (const float*)d_in[13]; const float* dec_b2 = (const float*)d_in[14];
    const float* enc_w1 = (const float*)d_in[15]; const float* enc_b1 = (const float*)d_in[16];
    const float* enc_w2 = (const float*)d_in[17]; const float* enc_b2 = (const float*)d_in[18];
    const float* ln[10]; for (int i = 0; i < 10; i++) ln[i] = (const float*)d_in[19 + i];
    (void)in_sizes; (void)n_in; (void)out_size; (void)ws_size;

    float* outC = (float*)d_out;
    float* outY = (float*)d_out + BTD;

    // ---- workspace pool (98.3 MB, proven safe) ----
    char* w = (char*)d_ws;
    u16*   qb   = (u16*)(w);
    u16*   kb   = (u16*)(w + 16 * MB);
    u16*   vb   = (u16*)(w + 32 * MB);
    u16*   tmpB = (u16*)(w + 48 * MB);
    u16*   hb64 = (u16*)(w);                  // 64 MB FFN hidden (full M)
    u16*   Kt2  = (u16*)(w + 32 * MB);        // cross K^T
    u16*   crossO= (u16*)(w + 32 * MB);       // cross attn out (after Kt2 dead)
    u16*   Vt2  = (u16*)(w + 48 * MB);        // cross V^T
    u16*   Nm   = (u16*)(w + 64 * MB);
    u16*   x1b  = (u16*)(w + 66 * MB);
    u16*   t2b  = (u16*)(w + 82 * MB);        // c1 / x2

    u16* w1o = (u16*)outY;                    //  8 MB bf16 w1 (outY scratch)
    u16* w2o = w1o + 4194304;                 //  8 MB bf16 w2
    u16* foutE = w1o + 8388608;               // 16 MB bf16 enc FFN out
    u16* foutD = x1b;                         // 16 MB bf16 dec FFN out

    // ---- 1) decoder masked self-attn: x1 = LN(X + attn(X)) ----
    k_proj<3><<<dim3(64, 6, 4), dim3(256), 0, stream>>>(
        X, Wh[0], Wh[1], Wh[2], qb, kb, vb);
    k_transpose2<<<dim3(T / 32, DH / 32, 16), dim3(256), 0, stream>>>(
        vb, tmpB, nullptr, nullptr);
    k_attn<1><<<dim3(256), dim3(512), 0, stream>>>(qb, kb, tmpB, vb, T, 0.0625f);
    k_addln<1, 0><<<dim3(Bn * T), dim3(256), 0, stream>>>(X, vb, ln[0], ln[1], nullptr, x1b);

    // ---- 2) encoder self-attn: c1 = LN(ctx + attn(ctx)) ----
    k_proj<3><<<dim3(64, 6, 4), dim3(256), 0, stream>>>(
        ctx, Wh[6], Wh[7], Wh[8], qb, kb, vb);
    k_transpose2<<<dim3(T / 32, DH / 32, 16), dim3(256), 0, stream>>>(
        vb, tmpB, nullptr, nullptr);
    k_attn<0><<<dim3(256), dim3(512), 0, stream>>>(qb, kb, tmpB, vb, T, 0.0625f);
    k_addln<1, 0><<<dim3(Bn * T), dim3(256), 0, stream>>>(ctx, vb, ln[6], ln[7], nullptr, t2b);

    // ---- 3) encoder FFN (full-M, R16 config): -> outC ----
    k_cast<<<dim3(4096), dim3(256), 0, stream>>>(enc_w1, w1o, 1048576);
    k_cast<<<dim3(4096), dim3(256), 0, stream>>>(enc_w2, w2o, 1048576);
    GEMM(0, 0, t2b, D, w1o, D, nullptr, hb64, 4096, enc_b1, 1, 0, 1.f,
         Bn * T, 4096, 1024, 1, 1, 0, 0, 0, 0, 0, 0);
    GEMM(0, 0, hb64, 4096, w2o, 4096, nullptr, foutE, 1024, enc_b2, 0, 0, 1.f,
         Bn * T, 1024, 4096, 1, 1, 0, 0, 0, 0, 0, 0);
    k_addln<0, 0><<<dim3(Bn * T), dim3(256), 0, stream>>>(
        t2b, foutE, ln[8], ln[9], outC, nullptr);

    // ---- 4) cross attention (no softmax): o = q (K^T V)^T / 16 ----
    GEMM(0, 1, x1b, D, Wh[3], DH, nullptr, qb, D, nullptr, 0, 0, 1.f,
         Bn * T, DH, DH, H, H, 0, DH, 0, DH * DH, 0, DH);
    k_proj<2><<<dim3(64, 4, 4), dim3(256), 0, stream>>>(
        outC, Wh[4], Wh[5], nullptr, kb, t2b, nullptr);
    k_transpose2<<<dim3(T / 32, DH / 32, 32), dim3(256), 0, stream>>>(
        kb, Kt2, t2b, Vt2);
    GEMM(0, 0, Vt2, T, Kt2, T, nullptr, Nm, DH, nullptr, 0, 0, 1.f,
         DH, DH, T, Bn * H, Bn * H, 0, (long)DH * T, 0, (long)DH * T, 0, DH * DH);
    GEMM(0, 0, qb, D, Nm, DH, nullptr, crossO, D, nullptr, 0, 0, 0.0625f,
         T, DH, DH, Bn * H, H, (long)T * D, DH, (long)H * DH * DH, DH * DH,
         (long)T * D, DH);
    k_addln<0, 0><<<dim3(Bn * T), dim3(256), 0, stream>>>(x1b, crossO, ln[2], ln[3], nullptr, t2b);

    // ---- 5) decoder FFN (full-M, R16 config): -> outY ----
    k_cast<<<dim3(4096), dim3(256), 0, stream>>>(dec_w1, w1o, 1048576);
    k_cast<<<dim3(4096), dim3(256), 0, stream>>>(dec_w2, w2o, 1048576);
    GEMM(0, 0, t2b, D, w1o, D, nullptr, hb64, 4096, dec_b1, 1, 0, 1.f,
         Bn * T, 4096, 1024, 1, 1, 0, 0, 0, 0, 0, 0);
    GEMM(0, 0, hb64, 4096, w2o, 4096, nullptr, foutD, 1024, dec_b2, 0, 0, 1.f,
         Bn * T, 1024, 4096, 1, 1, 0, 0, 0, 0, 0, 0);
    k_addln<0, 0><<<dim3(Bn * T), dim3(256), 0, stream>>>(
        t2b, foutD, ln[4], ln[5], outY, nullptr);
}